// Round 3
// baseline (2353.158 us; speedup 1.0000x reference)
//
#include <hip/hip_runtime.h>

// GCMC GraphConv layer, MI355X (gfx950).
// Math: h[dst] = sum_r ( (sum_{e: dst,r} x[src_e]) / c[dst,r] ) @ W[r]
// (identical to reference's sum_e (x@W)/c by linearity; fp reassociation only).
// Per direction (items->users, then users->items, reusing ONE accumulator):
//   1. memsetAsync zero of accum (+ both cnt arrays on first pass)
//   2. edge_scatter_dir: wave/edge, lane=feature, hardware-f32-atomicAdd of
//      x[src] into accum[dst,rate,feat]; lane0 counts edges per (dst,rate)
//   3. transform_nodes: dense [1,320]x[320,64] per node, W in 80 KB LDS,
//      lane = output feature, readlane broadcast of the A operand.

constexpr int FEAT = 64;   // IN_FEAT == HID_FEAT
constexpr int RC   = 5;    // rating classes

// Guarantee the hardware global_atomic_add_f32 (plain atomicAdd(float*) can
// fall back to a CAS loop depending on fp-atomic flags).
__device__ __forceinline__ void atomic_add_f32(float* p, float v) {
  unsafeAtomicAdd(p, v);
}

__global__ __launch_bounds__(256) void edge_scatter_dir(
    const float* __restrict__ src_x,     // [n_src, FEAT]
    const int* __restrict__ dst_idx,     // [E]
    const int* __restrict__ src_idx,     // [E]
    const int* __restrict__ rate,        // [E]
    float* __restrict__ accum,           // [n_dst, RC, FEAT] (pre-zeroed)
    int* __restrict__ cnt,               // [n_dst, RC]       (pre-zeroed)
    int n_edges)
{
  const int lane = threadIdx.x & 63;
  const int wid  = (blockIdx.x * blockDim.x + threadIdx.x) >> 6;
  const int nw   = (gridDim.x * blockDim.x) >> 6;
  for (int e = wid; e < n_edges; e += nw) {
    const int d = dst_idx[e];          // lane-uniform; HW broadcasts the load
    const int s = src_idx[e];
    const int r = rate[e];
    const float x = src_x[(size_t)s * FEAT + lane];       // coalesced 256B row
    atomic_add_f32(&accum[((size_t)d * RC + r) * FEAT + lane], x);
    if (lane == 0) atomicAdd(&cnt[d * RC + r], 1);
  }
}

__global__ __launch_bounds__(256) void transform_nodes(
    const float* __restrict__ accum,   // [n_nodes, RC, FEAT]
    const int* __restrict__ cnt,       // [n_nodes, RC]
    const float* __restrict__ W,       // [RC, FEAT, FEAT]  (r, in, out) row-major
    float* __restrict__ out,           // [n_nodes, FEAT]
    int n_nodes)
{
  extern __shared__ float Wlds[];      // RC*FEAT*FEAT floats = 80 KB
  constexpr int TOT = RC * FEAT * FEAT;
  for (int idx = threadIdx.x * 4; idx < TOT; idx += blockDim.x * 4) {
    *(float4*)&Wlds[idx] = *(const float4*)&W[idx];
  }
  __syncthreads();

  const int lane = threadIdx.x & 63;   // = output feature o
  const int wid  = (blockIdx.x * blockDim.x + threadIdx.x) >> 6;
  const int nw   = (gridDim.x * blockDim.x) >> 6;

  // 4 nodes per wave iteration; 100000 and 50000 are both divisible by 4.
  for (int base = wid * 4; base + 3 < n_nodes; base += nw * 4) {
    float a[4][RC];   // lane l holds accum[node, r, i=l] / c
#pragma unroll
    for (int n = 0; n < 4; ++n) {
      const int node = base + n;
#pragma unroll
      for (int r = 0; r < RC; ++r) {
        const float av = accum[((size_t)node * RC + r) * FEAT + lane];
        const int   c  = cnt[node * RC + r];
        a[n][r] = av * (1.0f / (float)(c > 0 ? c : 1));
      }
    }
    float o0 = 0.f, o1 = 0.f, o2 = 0.f, o3 = 0.f;
#pragma unroll
    for (int r = 0; r < RC; ++r) {
#pragma unroll
      for (int i = 0; i < FEAT; ++i) {
        const float w = Wlds[(r * FEAT + i) * FEAT + lane];  // 2-way bank alias: free
        o0 += __shfl(a[0][r], i) * w;   // compile-time srcLane -> v_readlane
        o1 += __shfl(a[1][r], i) * w;
        o2 += __shfl(a[2][r], i) * w;
        o3 += __shfl(a[3][r], i) * w;
      }
    }
    out[(size_t)(base + 0) * FEAT + lane] = o0;
    out[(size_t)(base + 1) * FEAT + lane] = o1;
    out[(size_t)(base + 2) * FEAT + lane] = o2;
    out[(size_t)(base + 3) * FEAT + lane] = o3;
  }
}

extern "C" void kernel_launch(void* const* d_in, const int* in_sizes, int n_in,
                              void* d_out, int out_size, void* d_ws, size_t ws_size,
                              hipStream_t stream) {
  const float* user_x = (const float*)d_in[0];
  const float* item_x = (const float*)d_in[1];
  const float* weight = (const float*)d_in[2];
  const int*   u_s    = (const int*)d_in[3];
  const int*   v_s    = (const int*)d_in[4];
  const int*   rate   = (const int*)d_in[5];

  const int n_users = in_sizes[0] / FEAT;   // 100000
  const int n_items = in_sizes[1] / FEAT;   // 50000
  const int n_edges = in_sizes[3];          // 1000000

  float* out = (float*)d_out;
  float* h_u = out;
  float* h_v = out + (size_t)n_users * FEAT;

  // Workspace: one accum buffer sized for the LARGER side, reused sequentially.
  // [ accum: max(n_users,n_items)*RC*FEAT floats | cnt_u | cnt_v ]  ~131 MB
  const int n_big = n_users > n_items ? n_users : n_items;
  float* accum = (float*)d_ws;
  int*   cnt_u = (int*)(accum + (size_t)n_big * RC * FEAT);
  int*   cnt_v = cnt_u + (size_t)n_users * RC;

  const size_t accum_v_bytes = (size_t)n_items * RC * FEAT * sizeof(float);
  const size_t zero1_bytes =
      (size_t)n_big * RC * FEAT * sizeof(float)
      + ((size_t)n_users * RC + (size_t)n_items * RC) * sizeof(int);

  const size_t lds_bytes = (size_t)RC * FEAT * FEAT * sizeof(float);  // 80 KB
  hipFuncSetAttribute(reinterpret_cast<const void*>(transform_nodes),
                      hipFuncAttributeMaxDynamicSharedMemorySize, (int)lds_bytes);

  // ---- direction 1: items -> users ----
  hipMemsetAsync(d_ws, 0, zero1_bytes, stream);
  edge_scatter_dir<<<2048, 256, 0, stream>>>(item_x, u_s, v_s, rate,
                                             accum, cnt_u, n_edges);
  transform_nodes<<<2048, 256, lds_bytes, stream>>>(accum, cnt_u, weight, h_u, n_users);

  // ---- direction 2: users -> items (reuse accum; stream order protects it) ----
  hipMemsetAsync(accum, 0, accum_v_bytes, stream);
  edge_scatter_dir<<<2048, 256, 0, stream>>>(user_x, v_s, u_s, rate,
                                             accum, cnt_v, n_edges);
  transform_nodes<<<1024, 256, lds_bytes, stream>>>(accum, cnt_v, weight, h_v, n_items);

  (void)ws_size; (void)n_in; (void)out_size;
}

// Round 10
// 627.917 us; speedup vs baseline: 3.7476x; 3.7476x over previous
//
#include <hip/hip_runtime.h>

// GCMC GraphConv layer, MI355X (gfx950) — atomic-free aggregation version.
// h[dst] = sum_r ( (sum_{e: dst,r} x[src_e]) / c[dst,r] ) @ W[r]
//
// 1. memset head_u/head_v to -1 (single hipMemsetAsync, 0xFF)
// 2. build_links: per edge, next[e] = atomicExch(&head[dst], e)  (int atomics)
// 3. aggregate_dir: wave per dst node, walk chain, gather x[src] rows
//    (coalesced 256B), accumulate per-rating in named registers, write
//    accum[d,r,:] = sum/count with plain stores (no f32 atomics, no memset)
// 4. transform_v3: h[d] = sum_r accum[d,r,:] @ W[r]; W column in VGPRs,
//    A read via wave-uniform float4 loads, pure v_fmac. No LDS anywhere.
// Users processed in 2 chunks of 50K over one 64 MB accum buffer (ws ~73 MB).

constexpr int FEAT  = 64;     // IN_FEAT == HID_FEAT
constexpr int RC    = 5;      // rating classes
constexpr int STRIP = 16;     // nodes per wave pass in transform
constexpr int CHUNK = 50000;  // nodes per accum chunk

// ---------- phase 2: linked-list build (both directions in one pass) ----------
__global__ __launch_bounds__(256) void build_links(
    const int* __restrict__ u_s, const int* __restrict__ v_s,
    int* __restrict__ head_u, int* __restrict__ head_v,
    int* __restrict__ next_u, int* __restrict__ next_v, int n_edges)
{
  const int e = blockIdx.x * blockDim.x + threadIdx.x;
  if (e >= n_edges) return;
  next_u[e] = atomicExch(&head_u[u_s[e]], e);
  next_v[e] = atomicExch(&head_v[v_s[e]], e);
}

// ---------- phase 3: gather-aggregate, one wave per destination node ----------
__global__ __launch_bounds__(256) void aggregate_dir(
    const float* __restrict__ src_x,    // [n_src, FEAT]
    const int* __restrict__ src_idx,    // [E] source node per edge
    const int* __restrict__ rate,       // [E]
    const int* __restrict__ head,       // [n_dst] list heads (-1 = empty)
    const int* __restrict__ next,       // [E] list links
    float* __restrict__ accum,          // [node_count, RC, FEAT] (chunk-local)
    int node_base, int node_count)
{
  const int lane = threadIdx.x & 63;
  const int w    = (blockIdx.x * blockDim.x + threadIdx.x) >> 6;  // wave id
  if (w >= node_count) return;
  const int d = node_base + w;

  // per-rating accumulators in NAMED registers (no runtime indexing -> no scratch)
  float a0 = 0.f, a1 = 0.f, a2 = 0.f, a3 = 0.f, a4 = 0.f;
  int   c0 = 0,   c1 = 0,   c2 = 0,   c3 = 0,   c4 = 0;

  for (int e = head[d]; e >= 0; e = next[e]) {   // wave-uniform chain walk
    const int s = src_idx[e];
    const int r = rate[e];
    const float xv = src_x[(size_t)s * FEAT + lane];  // coalesced 256B row
    a0 += (r == 0) ? xv : 0.f;  c0 += (r == 0);
    a1 += (r == 1) ? xv : 0.f;  c1 += (r == 1);
    a2 += (r == 2) ? xv : 0.f;  c2 += (r == 2);
    a3 += (r == 3) ? xv : 0.f;  c3 += (r == 3);
    a4 += (r == 4) ? xv : 0.f;  c4 += (r == 4);
  }

  float* row = accum + (size_t)w * RC * FEAT + lane;
  row[0 * FEAT] = a0 / (float)(c0 > 0 ? c0 : 1);
  row[1 * FEAT] = a1 / (float)(c1 > 0 ? c1 : 1);
  row[2 * FEAT] = a2 / (float)(c2 > 0 ? c2 : 1);
  row[3 * FEAT] = a3 / (float)(c3 > 0 ? c3 : 1);
  row[4 * FEAT] = a4 / (float)(c4 > 0 ? c4 : 1);
}

// ---------- phase 4: dense transform, accum pre-scaled (no cnt) ----------
// lane = output feature o; W[r] column for this lane in 64 VGPRs, amortized
// over a STRIP of nodes; A via wave-uniform float4 loads (SMEM-eligible).
__global__ __launch_bounds__(256) void transform_v3(
    const float* __restrict__ accum,   // [node_count, RC, FEAT]
    const float* __restrict__ W,       // [RC, FEAT, FEAT] (r, in, out)
    float* __restrict__ out,           // [node_count, FEAT] (chunk base applied)
    int node_count)
{
  const int lane = threadIdx.x & 63;
  const int wid  = (blockIdx.x * blockDim.x + threadIdx.x) >> 6;
  const int nw   = (gridDim.x * blockDim.x) >> 6;

  for (int base = wid * STRIP; base < node_count; base += nw * STRIP) {
    const int base_u = __builtin_amdgcn_readfirstlane(base);
    float o_acc[STRIP];
#pragma unroll
    for (int n = 0; n < STRIP; ++n) o_acc[n] = 0.f;

    for (int r = 0; r < RC; ++r) {   // not unrolled: keep W footprint at 64 VGPR
      float wcol[FEAT];
#pragma unroll
      for (int k = 0; k < FEAT; ++k)
        wcol[k] = W[((size_t)r * FEAT + k) * FEAT + lane];

#pragma unroll
      for (int n = 0; n < STRIP; ++n) {
        const int node = base_u + n;               // uniform
        if (node >= node_count) break;
        const float4* ap4 = reinterpret_cast<const float4*>(
            accum + ((size_t)node * RC + r) * FEAT);
        float t = 0.f;
#pragma unroll
        for (int k4 = 0; k4 < FEAT / 4; ++k4) {
          const float4 a = ap4[k4];                // uniform 16B load
          t = fmaf(a.x, wcol[k4 * 4 + 0], t);
          t = fmaf(a.y, wcol[k4 * 4 + 1], t);
          t = fmaf(a.z, wcol[k4 * 4 + 2], t);
          t = fmaf(a.w, wcol[k4 * 4 + 3], t);
        }
        o_acc[n] += t;
      }
    }
#pragma unroll
    for (int n = 0; n < STRIP; ++n) {
      if (base + n < node_count)
        out[(size_t)(base + n) * FEAT + lane] = o_acc[n];
    }
  }
}

extern "C" void kernel_launch(void* const* d_in, const int* in_sizes, int n_in,
                              void* d_out, int out_size, void* d_ws, size_t ws_size,
                              hipStream_t stream) {
  const float* user_x = (const float*)d_in[0];
  const float* item_x = (const float*)d_in[1];
  const float* weight = (const float*)d_in[2];
  const int*   u_s    = (const int*)d_in[3];
  const int*   v_s    = (const int*)d_in[4];
  const int*   rate   = (const int*)d_in[5];

  const int n_users = in_sizes[0] / FEAT;   // 100000
  const int n_items = in_sizes[1] / FEAT;   // 50000
  const int n_edges = in_sizes[3];          // 1000000

  float* out = (float*)d_out;
  float* h_u = out;
  float* h_v = out + (size_t)n_users * FEAT;

  // Workspace: [ accum 64MB | head_u | head_v | next_u | next_v ] ~73 MB
  float* accum  = (float*)d_ws;
  int*   head_u = (int*)(accum + (size_t)CHUNK * RC * FEAT);
  int*   head_v = head_u + n_users;
  int*   next_u = head_v + n_items;
  int*   next_v = next_u + n_edges;

  // heads -> -1 (0xFF byte pattern); next arrays fully written by build_links
  hipMemsetAsync(head_u, 0xFF, (size_t)(n_users + n_items) * sizeof(int), stream);

  build_links<<<(n_edges + 255) / 256, 256, 0, stream>>>(
      u_s, v_s, head_u, head_v, next_u, next_v, n_edges);

  // ---- users (items -> users), chunks of CHUNK nodes over one accum buffer
  for (int base = 0; base < n_users; base += CHUNK) {
    const int cnt = (n_users - base < CHUNK) ? (n_users - base) : CHUNK;
    aggregate_dir<<<(cnt + 3) / 4, 256, 0, stream>>>(
        item_x, v_s, rate, head_u, next_u, accum, base, cnt);
    transform_v3<<<(cnt + 63) / 64, 256, 0, stream>>>(
        accum, weight, h_u + (size_t)base * FEAT, cnt);
  }

  // ---- items (users -> items)
  for (int base = 0; base < n_items; base += CHUNK) {
    const int cnt = (n_items - base < CHUNK) ? (n_items - base) : CHUNK;
    aggregate_dir<<<(cnt + 3) / 4, 256, 0, stream>>>(
        user_x, u_s, rate, head_v, next_v, accum, base, cnt);
    transform_v3<<<(cnt + 63) / 64, 256, 0, stream>>>(
        accum, weight, h_v + (size_t)base * FEAT, cnt);
  }

  (void)ws_size; (void)n_in; (void)out_size;
}